// Round 6
// baseline (820.079 us; speedup 1.0000x reference)
//
#include <hip/hip_runtime.h>

#define B_  16
#define T_  2048
#define L_  128
#define M_  256
#define H_  512
#define F_  1024
#define EPS 1e-5f

// ---------------------------------------------------------------------------
// gemm128: 128x128 tile, BK=32, TM=TN=8, 256 threads, atomicAdd epilogue.
// VALU-bound inner loop: 64 FMA per 64B LDS read per thread per kk.
// amode: 0 row-major(lda); 1 gather x[b=r&15][T-1-(r>>4)][:];
//        2 tree row -> A[((r>>4)<<5)+16+(r&15)], epilogue adds Add[((r>>4)<<5)+(r&15)];
//        3 rows 0..M-2 from A, row M-1 from Aaux.
// kc==0 block adds bias/Add (if non-null). C leading dim = H_ (512) always.
// ---------------------------------------------------------------------------
#define LDS_P 132                      // 128+4, keeps b128 reads 16B-aligned
#define SM128 (32 * LDS_P * 2)

__device__ __forceinline__ float4 a_load(const float* __restrict__ A,
                                         const float* __restrict__ Aaux,
                                         int M, int lda, int amode,
                                         int gr, int gk) {
    if (gr >= M) return make_float4(0.f, 0.f, 0.f, 0.f);
    const float* p;
    if (amode == 1)
        p = A + (long)((gr & 15) * T_ + (T_ - 1 - (gr >> 4))) * L_ + gk;
    else if (amode == 2)
        p = A + (long)(((gr >> 4) << 5) + 16 + (gr & 15)) * lda + gk;
    else if (amode == 3 && gr == M - 1)
        p = Aaux + gk;
    else
        p = A + (long)gr * lda + gk;
    return *(const float4*)p;
}

__device__ __forceinline__ void gemm128(
    float* sm,
    const float* __restrict__ A, const float* __restrict__ Aaux,
    const float* __restrict__ B, const float* __restrict__ bias,
    const float* __restrict__ Add, float* __restrict__ C,
    int M, int lda, int kOff, int kLen, int amode, int kc, int bx, int by)
{
    float* As = sm;                    // [32][132] transposed: As[k][m]
    float* Bs = sm + 32 * LDS_P;       // [32][132]: Bs[k][n]
    const int tid = threadIdx.x;
    const int tx = tid & 15, ty = tid >> 4;
    const int row0 = by * 128, col0 = bx * 128;

    float4 pa[4], pb[4];
#pragma unroll
    for (int t = 0; t < 4; ++t) {
        int f = tid + t * 256;
        pa[t] = a_load(A, Aaux, M, lda, amode, row0 + (f >> 3), kOff + (f & 7) * 4);
        pb[t] = *(const float4*)(B + (long)(kOff + (f >> 5)) * H_ + col0 + (f & 31) * 4);
    }

    float acc[8][8] = {};

    for (int k0 = 0; k0 < kLen; k0 += 32) {
        __syncthreads();
#pragma unroll
        for (int t = 0; t < 4; ++t) {
            int f = tid + t * 256;
            int ar = f >> 3, ak = (f & 7) * 4;
            As[(ak + 0) * LDS_P + ar] = pa[t].x;
            As[(ak + 1) * LDS_P + ar] = pa[t].y;
            As[(ak + 2) * LDS_P + ar] = pa[t].z;
            As[(ak + 3) * LDS_P + ar] = pa[t].w;
            *(float4*)&Bs[(f >> 5) * LDS_P + (f & 31) * 4] = pb[t];
        }
        __syncthreads();
        int kn = k0 + 32;
        if (kn < kLen) {
#pragma unroll
            for (int t = 0; t < 4; ++t) {
                int f = tid + t * 256;
                pa[t] = a_load(A, Aaux, M, lda, amode, row0 + (f >> 3),
                               kOff + kn + (f & 7) * 4);
                pb[t] = *(const float4*)(B + (long)(kOff + kn + (f >> 5)) * H_ +
                                         col0 + (f & 31) * 4);
            }
        }
#pragma unroll
        for (int kk = 0; kk < 32; ++kk) {
            float ra[8], rb[8];
#pragma unroll
            for (int i = 0; i < 8; ++i) ra[i] = As[kk * LDS_P + ty * 8 + i];
#pragma unroll
            for (int j = 0; j < 8; ++j) rb[j] = Bs[kk * LDS_P + tx * 8 + j];
#pragma unroll
            for (int i = 0; i < 8; ++i)
#pragma unroll
                for (int j = 0; j < 8; ++j)
                    acc[i][j] = fmaf(ra[i], rb[j], acc[i][j]);
        }
    }

#pragma unroll
    for (int i = 0; i < 8; ++i) {
        int r = row0 + ty * 8 + i;
        if (r >= M) continue;
        long addoff = (amode == 2) ? (long)(((r >> 4) << 5) + (r & 15)) * H_ : 0;
#pragma unroll
        for (int j = 0; j < 8; ++j) {
            int c = col0 + tx * 8 + j;
            float v = acc[i][j];
            if (kc == 0 && bias) v += bias[c];
            if (kc == 0 && Add)  v += Add[addoff + c];
            atomicAdd(&C[(long)r * H_ + c], v);
        }
    }
}

// Dual-job: blocks [0,nA) = main job; blocks [nA, nA+64) = power matmul
// PO += PL@PR (512x512x512, split-4), riding the same stage.
__global__ __launch_bounds__(256) void dual128(
    const float* A, const float* Aaux, const float* B, const float* bias,
    const float* Add, float* C, int M, int lda, int kLen,
    int nbxA, int nrtA, int amode, int nA,
    const float* PL, const float* PR, float* PO)
{
    __shared__ float sm[SM128];
    int j = blockIdx.x;
    if (j < nA) {
        int bx = j % nbxA;
        int r  = j / nbxA;
        int by = r % nrtA;
        int kc = r / nrtA;
        gemm128(sm, A, Aaux, B, bias, Add, C, M, lda, kc * kLen, kLen,
                amode, kc, bx, by);
    } else {
        int s = j - nA;
        int bx = s & 3, by = (s >> 2) & 3, kc = s >> 4;
        gemm128(sm, PL, nullptr, PR, nullptr, nullptr, PO, 512, 512,
                kc * 128, 128, 0, kc, bx, by);
    }
}

// ---------------------------------------------------------------------------
// Thin tail split-K GEMM: BM=16, BN=64, BK=64, 4 outputs/thread, atomicAdd.
// MODE 0: A=[Y5 nodes1..3 | x_last] (K=1664), B=[P32;P64;P96;Wr] -> zacc
// MODE 1: A=zn (16x512), B=W1 -> hacc
// MODE 2: A=relu(b1+hacc) (16x1024), B=W2 -> out (+b2 on kc==0)
// ---------------------------------------------------------------------------
#define TLDA 20
#define TLDB 68
#define TSM (64 * TLDA + 64 * TLDB)

template <int MODE>
__device__ __forceinline__ float4 tail_a4(const float* __restrict__ Asrc,
                                          const float* __restrict__ aux,
                                          int b, int gk) {
    if (MODE == 0) {
        int seg = gk >> 9;
        if (seg < 3)
            return *(const float4*)(Asrc + (long)((seg + 1) * 16 + b) * H_ + (gk & 511));
        return *(const float4*)(aux + ((long)b * T_ + (T_ - 1)) * L_ + (gk - 1536));
    } else if (MODE == 1) {
        return *(const float4*)(Asrc + (long)b * H_ + gk);
    } else {
        float4 h = *(const float4*)(Asrc + (long)b * F_ + gk);
        float4 bb = *(const float4*)(aux + gk);
        return make_float4(fmaxf(h.x + bb.x, 0.f), fmaxf(h.y + bb.y, 0.f),
                           fmaxf(h.z + bb.z, 0.f), fmaxf(h.w + bb.w, 0.f));
    }
}

template <int MODE>
__device__ __forceinline__ float4 tail_b4(const float* __restrict__ P32,
                                          const float* __restrict__ P64,
                                          const float* __restrict__ P96,
                                          const float* __restrict__ WB,
                                          int kr, int c) {
    if (MODE == 0) {
        const float* p;
        if (kr < 512)       p = P32 + (long)kr * H_;
        else if (kr < 1024) p = P64 + (long)(kr - 512) * H_;
        else if (kr < 1536) p = P96 + (long)(kr - 1024) * H_;
        else                p = WB + (long)(kr - 1536) * H_;
        return *(const float4*)(p + c);
    } else if (MODE == 1) {
        return *(const float4*)(WB + (long)kr * F_ + c);
    } else {
        return *(const float4*)(WB + (long)kr * H_ + c);
    }
}

template <int MODE>
__global__ __launch_bounds__(256) void tailgemm(
    const float* __restrict__ Asrc, const float* __restrict__ aux,
    const float* __restrict__ P32, const float* __restrict__ P64,
    const float* __restrict__ P96, const float* __restrict__ WB,
    const float* __restrict__ bias2, float* __restrict__ Cacc,
    int nbx, int kLen)
{
    constexpr int LDC = (MODE == 1) ? F_ : H_;
    __shared__ float sm[TSM];
    float* As = sm;                    // [64][20]
    float* Bs = sm + 64 * TLDA;        // [64][68]
    const int tid = threadIdx.x;
    const int tx = tid & 15, ty = tid >> 4;
    const int kc = blockIdx.x / nbx;
    const int col0 = (blockIdx.x % nbx) * 64;
    const int kOff = kc * kLen;

    float4 pa, pb[4];
    pa = tail_a4<MODE>(Asrc, aux, ty, kOff + tx * 4);
#pragma unroll
    for (int t = 0; t < 4; ++t) {
        int f = tid + t * 256;
        pb[t] = tail_b4<MODE>(P32, P64, P96, WB, kOff + (f >> 4), col0 + (f & 15) * 4);
    }

    float acc[4] = {};
    for (int k0 = 0; k0 < kLen; k0 += 64) {
        __syncthreads();
        {
            int kk = tx * 4;
            As[(kk + 0) * TLDA + ty] = pa.x;
            As[(kk + 1) * TLDA + ty] = pa.y;
            As[(kk + 2) * TLDA + ty] = pa.z;
            As[(kk + 3) * TLDA + ty] = pa.w;
        }
#pragma unroll
        for (int t = 0; t < 4; ++t) {
            int f = tid + t * 256;
            *(float4*)&Bs[(f >> 4) * TLDB + (f & 15) * 4] = pb[t];
        }
        __syncthreads();
        int kn = k0 + 64;
        if (kn < kLen) {
            pa = tail_a4<MODE>(Asrc, aux, ty, kOff + kn + tx * 4);
#pragma unroll
            for (int t = 0; t < 4; ++t) {
                int f = tid + t * 256;
                pb[t] = tail_b4<MODE>(P32, P64, P96, WB, kOff + kn + (f >> 4),
                                      col0 + (f & 15) * 4);
            }
        }
#pragma unroll
        for (int kk = 0; kk < 64; ++kk) {
            float ra = As[kk * TLDA + ty];
            float4 rb = *(float4*)&Bs[kk * TLDB + tx * 4];
            acc[0] = fmaf(ra, rb.x, acc[0]);
            acc[1] = fmaf(ra, rb.y, acc[1]);
            acc[2] = fmaf(ra, rb.z, acc[2]);
            acc[3] = fmaf(ra, rb.w, acc[3]);
        }
    }

    float* dst = Cacc + (long)ty * LDC + col0 + tx * 4;
#pragma unroll
    for (int q = 0; q < 4; ++q) {
        float v = acc[q];
        if (MODE == 2 && kc == 0 && bias2) v += bias2[col0 + tx * 4 + q];
        atomicAdd(dst + q, v);
    }
}

// z = Y5node0 + zacc + br ; LayerNorm -> zn.  grid=16
__global__ __launch_bounds__(256) void zlnred(
    const float* __restrict__ Y5, const float* __restrict__ zacc,
    const float* __restrict__ br, const float* __restrict__ lng,
    const float* __restrict__ lnb, float* __restrict__ zn)
{
    __shared__ float red1[4], red2[4];
    const int b = blockIdx.x, tid = threadIdx.x;
    float z[2];
#pragma unroll
    for (int jj = 0; jj < 2; ++jj) {
        int c = tid + jj * 256;
        z[jj] = Y5[(long)b * H_ + c] + zacc[(long)b * H_ + c] + br[c];
    }
    float s1 = z[0] + z[1];
    float s2 = z[0] * z[0] + z[1] * z[1];
#pragma unroll
    for (int off = 32; off > 0; off >>= 1) {
        s1 += __shfl_down(s1, off, 64);
        s2 += __shfl_down(s2, off, 64);
    }
    int wid = tid >> 6, lane = tid & 63;
    if (lane == 0) { red1[wid] = s1; red2[wid] = s2; }
    __syncthreads();
    float S1 = red1[0] + red1[1] + red1[2] + red1[3];
    float S2 = red2[0] + red2[1] + red2[2] + red2[3];
    float mu  = S1 * (1.0f / H_);
    float var = S2 * (1.0f / H_) - mu * mu;
    float rs  = rsqrtf(var + EPS);
#pragma unroll
    for (int jj = 0; jj < 2; ++jj) {
        int c = tid + jj * 256;
        zn[(long)b * H_ + c] = (z[jj] - mu) * rs * lng[c] + lnb[c];
    }
}

// Zero the accumulation region of ws + d_out.
__global__ __launch_bounds__(256) void zerok(float4* w, long n4, float4* o, long n4o)
{
    long stride = (long)gridDim.x * 256;
    for (long i = (long)blockIdx.x * 256 + threadIdx.x; i < n4; i += stride)
        w[i] = make_float4(0.f, 0.f, 0.f, 0.f);
    for (long i = (long)blockIdx.x * 256 + threadIdx.x; i < n4o; i += stride)
        o[i] = make_float4(0.f, 0.f, 0.f, 0.f);
}

// ---------------------------------------------------------------------------
extern "C" void kernel_launch(void* const* d_in, const int* in_sizes, int n_in,
                              void* d_out, int out_size, void* d_ws, size_t ws_size,
                              hipStream_t stream) {
    const float* x    = (const float*)d_in[0];
    const float* We   = (const float*)d_in[1];
    const float* be   = (const float*)d_in[2];
    const float* Wb   = (const float*)d_in[3];
    const float* Amat = (const float*)d_in[4];
    const float* Wr   = (const float*)d_in[5];
    const float* br   = (const float*)d_in[6];
    const float* lng  = (const float*)d_in[7];
    const float* lnb  = (const float*)d_in[8];
    const float* W1   = (const float*)d_in[9];
    const float* b1   = (const float*)d_in[10];
    const float* W2   = (const float*)d_in[11];
    const float* b2   = (const float*)d_in[12];
    float* out = (float*)d_out;

    float* ws   = (float*)d_ws;
    float* Wc   = ws;                        // 129x512 (row 128 = be@Wb)
    float* P2   = Wc + 129 * H_;
    float* P4   = P2 + H_ * H_;
    float* P8   = P4 + H_ * H_;
    float* P16  = P8 + H_ * H_;
    float* P32  = P16 + H_ * H_;
    float* P64  = P32 + H_ * H_;
    float* P96  = P64 + H_ * H_;
    float* Y1   = P96 + H_ * H_;             // 1024x512
    float* Y2   = Y1 + 1024 * H_;            // 512x512
    float* Y3   = Y2 + 512 * H_;             // 256x512
    float* Y4   = Y3 + 256 * H_;             // 128x512
    float* Y5   = Y4 + 128 * H_;             // 64x512
    float* zacc = Y5 + 64 * H_;              // 16x512
    float* hacc = zacc + B_ * H_;            // 16x1024
    float* U0   = hacc + B_ * F_;            // 2048x512 (atomic too -> zeroed)
    float* zn   = U0 + 2048 * H_;            // 16x512 (plain write)
    long zeroN = (long)(zn - ws);            // floats to zero (ends at U0 end)

    // Z: zero accumulation buffers + out
    zerok<<<1024, 256, 0, stream>>>((float4*)ws, zeroN / 4, (float4*)out,
                                    (long)out_size / 4);
    // S0: Wc += [We;be]@Wb (129x512,K=256,split2) [16] || P2 += A@A [64]
    dual128<<<80, 256, 0, stream>>>(We, be, Wb, nullptr, nullptr, Wc,
                                    129, M_, 128, 4, 2, 3, 16, Amat, Amat, P2);
    // S1: U0 += gather(x)@Wc + bc (2048x512,K=128) [64] || P4 += P2@P2 [64]
    dual128<<<128, 256, 0, stream>>>(x, nullptr, Wc, Wc + 128 * H_, nullptr, U0,
                                     2048, 0, 128, 4, 16, 1, 64, P2, P2, P4);
    // S2: Y1 += tree(U0)@A + U0even (1024 rows, split4) [128] || P8 [64]
    dual128<<<192, 256, 0, stream>>>(U0, nullptr, Amat, nullptr, U0, Y1,
                                     1024, H_, 128, 4, 8, 2, 128, P4, P4, P8);
    // S3: Y2 += tree(Y1)@P2 + Y1even (512 rows) [64] || P16 [64]
    dual128<<<128, 256, 0, stream>>>(Y1, nullptr, P2, nullptr, Y1, Y2,
                                     512, H_, 128, 4, 4, 2, 64, P8, P8, P16);
    // S4: Y3 += tree(Y2)@P4 + Y2even (256 rows) [32] || P32 [64]
    dual128<<<96, 256, 0, stream>>>(Y2, nullptr, P4, nullptr, Y2, Y3,
                                    256, H_, 128, 4, 2, 2, 32, P16, P16, P32);
    // S5: Y4 += tree(Y3)@P8 + Y3even (128 rows) [16] || P64 [64]
    dual128<<<80, 256, 0, stream>>>(Y3, nullptr, P8, nullptr, Y3, Y4,
                                    128, H_, 128, 4, 1, 2, 16, P32, P32, P64);
    // S6: Y5 += tree(Y4)@P16 + Y4even (64 rows) [16] || P96 += P32@P64 [64]
    dual128<<<80, 256, 0, stream>>>(Y4, nullptr, P16, nullptr, Y4, Y5,
                                    64, H_, 128, 4, 1, 2, 16, P32, P64, P96);
    // S7: zacc += [Y5n1..3|x_last]@[P32;P64;P96;Wr] (K=1664, 13x8 blocks)
    tailgemm<0><<<104, 256, 0, stream>>>(Y5, x, P32, P64, P96, Wr, nullptr,
                                         zacc, 8, 128);
    // S7b: z = Y5node0 + zacc + br ; LN -> zn
    zlnred<<<16, 256, 0, stream>>>(Y5, zacc, br, lng, lnb, zn);
    // S8: hacc += zn@W1 (K=512, 4x16 blocks)
    tailgemm<1><<<64, 256, 0, stream>>>(zn, nullptr, nullptr, nullptr, nullptr,
                                        W1, nullptr, hacc, 16, 128);
    // S9: out += relu(b1+hacc)@W2 + b2 (K=1024, 8x8 blocks)
    tailgemm<2><<<64, 256, 0, stream>>>(hacc, b1, nullptr, nullptr, nullptr,
                                        W2, b2, out, 8, 128);
}

// Round 7
// 428.171 us; speedup vs baseline: 1.9153x; 1.9153x over previous
//
#include <hip/hip_runtime.h>

#define B_  16
#define T_  2048
#define L_  128
#define H_  512
#define F_  1024
#define EPS 1e-5f

#define GP   68                 // 64+4 LDS pad
#define GSM  (64 * GP * 2)      // 8704 floats = 34816 B

// ---------------------------------------------------------------------------
// Job descriptor for the generic 64x64-tile GEMM (BK=64, TM=TN=4, 256 thr).
// amode: 0 = A row-major(lda); 1 = rows<128 from A(lda), row 128 from Aaux,
//        rows>128 zero; 2 = x-gather: row r=(j*16+b), k=(i*128+inner) ->
//        x[b][T-1-(16j+i)][inner]; 9 = T1 init: C = A + I (elementwise).
// emode: 0 = C[kc*M*512 + r*512+c]; 1 = row<128 -> C, row==128 -> C2 (bc).
// Add (optional): epilogue += Add[r*512+c]  (T-chain).
// ---------------------------------------------------------------------------
struct Job {
    const float* A; const float* Aaux; const float* B;
    const float* Add; float* C; float* C2;
    int M, lda, kLen, nbx, nrt, amode, emode;
};

__device__ __forceinline__ float4 jload(const Job& jb, int gr, int gk) {
    if (jb.amode == 1) {
        if (gr < 128)  return *(const float4*)(jb.A + (long)gr * jb.lda + gk);
        if (gr == 128) return *(const float4*)(jb.Aaux + gk);
        return make_float4(0.f, 0.f, 0.f, 0.f);
    } else if (jb.amode == 2) {
        int j = gr >> 4, b = gr & 15;
        int i = gk >> 7, inner = gk & 127;
        int t = T_ - 1 - (16 * j + i);
        return *(const float4*)(jb.A + ((long)b * T_ + t) * L_ + inner);
    } else {
        if (gr >= jb.M) return make_float4(0.f, 0.f, 0.f, 0.f);
        return *(const float4*)(jb.A + (long)gr * jb.lda + gk);
    }
}

__device__ __forceinline__ void g64run(float* sm, const Job& jb, int rel) {
    float* As = sm;                 // [64][68] transposed: As[k][m]
    float* Bs = sm + 64 * GP;       // [64][68]: Bs[k][n]
    const int tid = threadIdx.x, tx = tid & 15, ty = tid >> 4;
    const int bx = rel % jb.nbx;
    const int r  = rel / jb.nbx;
    const int by = r % jb.nrt;
    const int kc = r / jb.nrt;
    const int row0 = by * 64, col0 = bx * 64, kOff = kc * jb.kLen;

    float4 pa[4], pb[4];
#pragma unroll
    for (int t = 0; t < 4; ++t) {
        int f = tid + t * 256;
        pa[t] = jload(jb, row0 + (f >> 4), kOff + (f & 15) * 4);
        pb[t] = *(const float4*)(jb.B + (long)(kOff + (f >> 4)) * H_ + col0 + (f & 15) * 4);
    }
    float acc[4][4] = {};
    for (int k0 = 0; k0 < jb.kLen; k0 += 64) {
        __syncthreads();
#pragma unroll
        for (int t = 0; t < 4; ++t) {
            int f = tid + t * 256;
            int ar = f >> 4, ak = (f & 15) * 4;
            As[(ak + 0) * GP + ar] = pa[t].x;
            As[(ak + 1) * GP + ar] = pa[t].y;
            As[(ak + 2) * GP + ar] = pa[t].z;
            As[(ak + 3) * GP + ar] = pa[t].w;
            *(float4*)&Bs[(f >> 4) * GP + (f & 15) * 4] = pb[t];
        }
        __syncthreads();
        int kn = k0 + 64;
        if (kn < jb.kLen) {
#pragma unroll
            for (int t = 0; t < 4; ++t) {
                int f = tid + t * 256;
                pa[t] = jload(jb, row0 + (f >> 4), kOff + kn + (f & 15) * 4);
                pb[t] = *(const float4*)(jb.B + (long)(kOff + kn + (f >> 4)) * H_ +
                                         col0 + (f & 15) * 4);
            }
        }
#pragma unroll
        for (int kk = 0; kk < 64; ++kk) {
            float4 ra = *(float4*)&As[kk * GP + ty * 4];
            float4 rb = *(float4*)&Bs[kk * GP + tx * 4];
            acc[0][0] = fmaf(ra.x, rb.x, acc[0][0]);
            acc[0][1] = fmaf(ra.x, rb.y, acc[0][1]);
            acc[0][2] = fmaf(ra.x, rb.z, acc[0][2]);
            acc[0][3] = fmaf(ra.x, rb.w, acc[0][3]);
            acc[1][0] = fmaf(ra.y, rb.x, acc[1][0]);
            acc[1][1] = fmaf(ra.y, rb.y, acc[1][1]);
            acc[1][2] = fmaf(ra.y, rb.z, acc[1][2]);
            acc[1][3] = fmaf(ra.y, rb.w, acc[1][3]);
            acc[2][0] = fmaf(ra.z, rb.x, acc[2][0]);
            acc[2][1] = fmaf(ra.z, rb.y, acc[2][1]);
            acc[2][2] = fmaf(ra.z, rb.z, acc[2][2]);
            acc[2][3] = fmaf(ra.z, rb.w, acc[2][3]);
            acc[3][0] = fmaf(ra.w, rb.x, acc[3][0]);
            acc[3][1] = fmaf(ra.w, rb.y, acc[3][1]);
            acc[3][2] = fmaf(ra.w, rb.z, acc[3][2]);
            acc[3][3] = fmaf(ra.w, rb.w, acc[3][3]);
        }
    }
    long coff = (long)kc * jb.M * H_;
#pragma unroll
    for (int i = 0; i < 4; ++i) {
        int rr = row0 + ty * 4 + i;
        if (rr >= jb.M) continue;
        int c = col0 + tx * 4;
        float4 v = make_float4(acc[i][0], acc[i][1], acc[i][2], acc[i][3]);
        if (jb.Add) {
            float4 ad = *(const float4*)(jb.Add + (long)rr * H_ + c);
            v.x += ad.x; v.y += ad.y; v.z += ad.z; v.w += ad.w;
        }
        if (jb.emode == 1 && rr == 128)
            *(float4*)(jb.C2 + c) = v;
        else
            *(float4*)(jb.C + coff + (long)rr * H_ + c) = v;
    }
}

struct Pack { Job j[4]; int n0, n1, n2, n3; };

__global__ __launch_bounds__(256) void gstage(Pack p) {
    __shared__ float sm[GSM];
    int b = blockIdx.x, rel;
    const Job* jb;
    if (b < p.n0) { jb = &p.j[0]; rel = b; }
    else if (b < p.n0 + p.n1) { jb = &p.j[1]; rel = b - p.n0; }
    else if (b < p.n0 + p.n1 + p.n2) { jb = &p.j[2]; rel = b - p.n0 - p.n1; }
    else { jb = &p.j[3]; rel = b - p.n0 - p.n1 - p.n2; }
    if (jb->amode == 9) {          // T1 = A + I, grid-stride over 512^2
        for (int idx = rel * 256 + threadIdx.x; idx < H_ * H_; idx += 8 * 256) {
            int row = idx >> 9, col = idx & 511;
            jb->C[idx] = jb->A[idx] + (row == col ? 1.f : 0.f);
        }
        return;
    }
    g64run(sm, *jb, rel);
}

// ---------------------------------------------------------------------------
// Thin tail kernels: BM=16 rows/group, BN=64, BK=64, 4 out/thread, split-K,
// deterministic slab outputs parts[kc][ROWS][LDC].
// MODE 0 (H): A = Gsum rows (4v+u+1), B = {C,C2,C3}, K=1536, nrg=2
// MODE 1 (z): A = [H1|bc|x_last], B = [C4;T7;Wr], K=1152
// MODE 2 (MLP1): A = zn, B = W1 (ldb=1024)
// MODE 3 (MLP2): A = relu(b1+sum h1p), B = W2
// ---------------------------------------------------------------------------
struct TP {
    const float* G; const float* Hp; const float* C1; const float* C2p;
    const float* C3; const float* C4; const float* T7; const float* bc;
    const float* x; const float* Wr; const float* zn; const float* W1;
    const float* h1p; const float* b1; const float* W2;
    float* outp;
    int nbx, nrg, kLen;
};

template <int MODE>
__device__ __forceinline__ float4 ta4(const TP& tp, int rg, int b, int gk) {
    if (MODE == 0) {
        int u = gk >> 9, inner = gk & 511;
        int r = (4 * rg + u + 1) * 16 + b;
        float4 s = make_float4(0.f, 0.f, 0.f, 0.f);
#pragma unroll
        for (int q = 0; q < 4; ++q) {
            float4 g = *(const float4*)(tp.G + (long)q * 128 * H_ + (long)r * H_ + inner);
            s.x += g.x; s.y += g.y; s.z += g.z; s.w += g.w;
        }
        return s;
    } else if (MODE == 1) {
        if (gk < 512) {
            float4 s = make_float4(0.f, 0.f, 0.f, 0.f);
#pragma unroll
            for (int q = 0; q < 3; ++q) {
                float4 h = *(const float4*)(tp.Hp + (long)q * 32 * H_ + (long)(16 + b) * H_ + gk);
                s.x += h.x; s.y += h.y; s.z += h.z; s.w += h.w;
            }
#pragma unroll
            for (int q = 0; q < 4; ++q) {
                float4 g = *(const float4*)(tp.G + (long)q * 128 * H_ + (long)(64 + b) * H_ + gk);
                s.x += g.x; s.y += g.y; s.z += g.z; s.w += g.w;
            }
            return s;
        } else if (gk < 1024) {
            return *(const float4*)(tp.bc + gk - 512);
        } else {
            return *(const float4*)(tp.x + ((long)b * T_ + T_ - 1) * L_ + gk - 1024);
        }
    } else if (MODE == 2) {
        return *(const float4*)(tp.zn + (long)b * H_ + gk);
    } else {
        float4 s = *(const float4*)(tp.b1 + gk);
#pragma unroll
        for (int q = 0; q < 4; ++q) {
            float4 h = *(const float4*)(tp.h1p + (long)q * 16 * F_ + (long)b * F_ + gk);
            s.x += h.x; s.y += h.y; s.z += h.z; s.w += h.w;
        }
        return make_float4(fmaxf(s.x, 0.f), fmaxf(s.y, 0.f),
                           fmaxf(s.z, 0.f), fmaxf(s.w, 0.f));
    }
}

template <int MODE>
__device__ __forceinline__ float4 tb4(const TP& tp, int gk, int c) {
    if (MODE == 0) {
        int u = gk >> 9, inner = gk & 511;
        const float* P = (u == 0) ? tp.C1 : (u == 1) ? tp.C2p : tp.C3;
        return *(const float4*)(P + (long)inner * H_ + c);
    } else if (MODE == 1) {
        if (gk < 512)  return *(const float4*)(tp.C4 + (long)gk * H_ + c);
        if (gk < 1024) return *(const float4*)(tp.T7 + (long)(gk - 512) * H_ + c);
        return *(const float4*)(tp.Wr + (long)(gk - 1024) * H_ + c);
    } else if (MODE == 2) {
        return *(const float4*)(tp.W1 + (long)gk * F_ + c);
    } else {
        return *(const float4*)(tp.W2 + (long)gk * H_ + c);
    }
}

template <int MODE, bool GJOB>
__global__ __launch_bounds__(256) void tstage(TP tp, Job gj, int nThin) {
    __shared__ float sm[GSM];
    int blk = blockIdx.x;
    if (GJOB && blk >= nThin) { g64run(sm, gj, blk - nThin); return; }
    float* As = sm;                  // [64][20]
    float* Bs = sm + 64 * 20;        // [64][68]
    const int tid = threadIdx.x, tx = tid & 15, ty = tid >> 4;
    const int bx = blk % tp.nbx;
    const int rr = blk / tp.nbx;
    const int rg = rr % tp.nrg;
    const int kc = rr / tp.nrg;
    const int col0 = bx * 64, kOff = kc * tp.kLen;
    constexpr int LDC  = (MODE == 2) ? F_ : H_;
    constexpr int ROWS = (MODE == 0) ? 32 : 16;

    float4 pa, pb[4];
    pa = ta4<MODE>(tp, rg, ty, kOff + tx * 4);
#pragma unroll
    for (int t = 0; t < 4; ++t) {
        int f = tid + t * 256;
        pb[t] = tb4<MODE>(tp, kOff + (f >> 4), col0 + (f & 15) * 4);
    }
    float acc[4] = {};
    for (int k0 = 0; k0 < tp.kLen; k0 += 64) {
        __syncthreads();
        {
            int kk = tx * 4;
            As[(kk + 0) * 20 + ty] = pa.x;
            As[(kk + 1) * 20 + ty] = pa.y;
            As[(kk + 2) * 20 + ty] = pa.z;
            As[(kk + 3) * 20 + ty] = pa.w;
        }
#pragma unroll
        for (int t = 0; t < 4; ++t) {
            int f = tid + t * 256;
            *(float4*)&Bs[(f >> 4) * 68 + (f & 15) * 4] = pb[t];
        }
        __syncthreads();
        int kn = k0 + 64;
        if (kn < tp.kLen) {
            pa = ta4<MODE>(tp, rg, ty, kOff + kn + tx * 4);
#pragma unroll
            for (int t = 0; t < 4; ++t) {
                int f = tid + t * 256;
                pb[t] = tb4<MODE>(tp, kOff + kn + (f >> 4), col0 + (f & 15) * 4);
            }
        }
#pragma unroll
        for (int kk = 0; kk < 64; ++kk) {
            float ra = As[kk * 20 + ty];
            float4 rb = *(float4*)&Bs[kk * 68 + tx * 4];
            acc[0] = fmaf(ra, rb.x, acc[0]);
            acc[1] = fmaf(ra, rb.y, acc[1]);
            acc[2] = fmaf(ra, rb.z, acc[2]);
            acc[3] = fmaf(ra, rb.w, acc[3]);
        }
    }
    float* dst = tp.outp + (long)kc * ROWS * LDC + (long)(rg * 16 + ty) * LDC +
                 col0 + tx * 4;
    *(float4*)dst = make_float4(acc[0], acc[1], acc[2], acc[3]);
}

// z = br + sum(9 zp) + H0(sum 3 Hp rows v=0) + G0(sum 4 slabs); LN -> zn
__global__ __launch_bounds__(256) void zln(
    const float* __restrict__ zp, const float* __restrict__ Hp,
    const float* __restrict__ G, const float* __restrict__ br,
    const float* __restrict__ lng, const float* __restrict__ lnb,
    float* __restrict__ zn)
{
    __shared__ float red1[4], red2[4];
    const int b = blockIdx.x, tid = threadIdx.x;
    float z[2];
#pragma unroll
    for (int jj = 0; jj < 2; ++jj) {
        int c = tid + jj * 256;
        float s = br[c];
#pragma unroll
        for (int q = 0; q < 9; ++q) s += zp[(long)q * 16 * H_ + (long)b * H_ + c];
#pragma unroll
        for (int q = 0; q < 3; ++q) s += Hp[(long)q * 32 * H_ + (long)b * H_ + c];
#pragma unroll
        for (int q = 0; q < 4; ++q) s += G[(long)q * 128 * H_ + (long)b * H_ + c];
        z[jj] = s;
    }
    float s1 = z[0] + z[1];
    float s2 = z[0] * z[0] + z[1] * z[1];
#pragma unroll
    for (int off = 32; off > 0; off >>= 1) {
        s1 += __shfl_down(s1, off, 64);
        s2 += __shfl_down(s2, off, 64);
    }
    int wid = tid >> 6, lane = tid & 63;
    if (lane == 0) { red1[wid] = s1; red2[wid] = s2; }
    __syncthreads();
    float S1 = red1[0] + red1[1] + red1[2] + red1[3];
    float S2 = red2[0] + red2[1] + red2[2] + red2[3];
    float mu  = S1 * (1.0f / H_);
    float var = S2 * (1.0f / H_) - mu * mu;
    float rs  = rsqrtf(var + EPS);
#pragma unroll
    for (int jj = 0; jj < 2; ++jj) {
        int c = tid + jj * 256;
        zn[(long)b * H_ + c] = (z[jj] - mu) * rs * lng[c] + lnb[c];
    }
}

// out = b2 + sum(8 op slabs)
__global__ __launch_bounds__(256) void ored(
    const float* __restrict__ op, const float* __restrict__ b2,
    float* __restrict__ out)
{
    int b = blockIdx.x >> 1;
    int c = (blockIdx.x & 1) * 256 + threadIdx.x;
    float s = b2[c];
#pragma unroll
    for (int q = 0; q < 8; ++q) s += op[(long)q * 16 * H_ + (long)b * H_ + c];
    out[(long)b * H_ + c] = s;
}

// ---------------------------------------------------------------------------
extern "C" void kernel_launch(void* const* d_in, const int* in_sizes, int n_in,
                              void* d_out, int out_size, void* d_ws, size_t ws_size,
                              hipStream_t stream) {
    const float* x    = (const float*)d_in[0];
    const float* We   = (const float*)d_in[1];
    const float* be   = (const float*)d_in[2];
    const float* Wb   = (const float*)d_in[3];
    const float* Amat = (const float*)d_in[4];
    const float* Wr   = (const float*)d_in[5];
    const float* br   = (const float*)d_in[6];
    const float* lng  = (const float*)d_in[7];
    const float* lnb  = (const float*)d_in[8];
    const float* W1   = (const float*)d_in[9];
    const float* b1   = (const float*)d_in[10];
    const float* W2   = (const float*)d_in[11];
    const float* b2   = (const float*)d_in[12];
    float* out = (float*)d_out;

    float* ws    = (float*)d_ws;
    float* stack = ws;                       // 2048x512 (S0..S15, 128-row units)
    float* bc    = stack + 2048 * H_;        // 512
    float* P2    = bc + H_;                  // each 512x512:
    float* P4    = P2 + H_ * H_;
    float* P8    = P4 + H_ * H_;
    float* C1    = P8 + H_ * H_;             // A^16
    float* C2p   = C1 + H_ * H_;             // A^32
    float* C3    = C2p + H_ * H_;            // A^48
    float* C4    = C3 + H_ * H_;             // A^64
    float* T1    = C4 + H_ * H_;             // T_l = sum_{k<2^l} A^k
    float* T2    = T1 + H_ * H_;
    float* T3    = T2 + H_ * H_;
    float* T4    = T3 + H_ * H_;
    float* T5    = T4 + H_ * H_;
    float* T6    = T5 + H_ * H_;
    float* T7    = T6 + H_ * H_;
    float* G     = T7 + H_ * H_;             // 4 slabs x 128 x 512
    float* Hp    = G + 4 * 128 * H_;         // 3 slabs x 32 x 512
    float* zp    = Hp + 3 * 32 * H_;         // 9 slabs x 16 x 512
    float* zn    = zp + 9 * B_ * H_;         // 16 x 512
    float* h1p   = zn + B_ * H_;             // 4 slabs x 16 x 1024
    float* op    = h1p + 4 * B_ * F_;        // 8 slabs x 16 x 512

    Job dummy = {};
    dummy.M = 0; dummy.nbx = 1; dummy.nrt = 1; dummy.kLen = 64; dummy.amode = 0;

    // K1: Wc=[We;be]@Wb -> stack rows0..127 + bc  ||  P2=A@A  ||  T1=A+I
    {
        Pack p; p.j[3] = dummy;
        p.j[0] = {We, be, Wb, nullptr, stack, bc, 129, 256, 256, 8, 3, 1, 1};
        p.j[1] = {Amat, nullptr, Amat, nullptr, P2, nullptr, 512, 512, 512, 8, 8, 0, 0};
        p.j[2] = {Amat, nullptr, nullptr, nullptr, T1, nullptr, 512, 512, 64, 1, 1, 9, 0};
        p.n0 = 24; p.n1 = 64; p.n2 = 8; p.n3 = 0;
        gstage<<<96, 256, 0, stream>>>(p);
    }
    // K2: S1 = S0@A  ||  P4 = P2@P2  ||  T2 = T1 + T1@P2
    {
        Pack p; p.j[3] = dummy;
        p.j[0] = {stack, nullptr, Amat, nullptr, stack + 128 * H_, nullptr, 128, 512, 512, 8, 2, 0, 0};
        p.j[1] = {P2, nullptr, P2, nullptr, P4, nullptr, 512, 512, 512, 8, 8, 0, 0};
        p.j[2] = {T1, nullptr, P2, T1, T2, nullptr, 512, 512, 512, 8, 8, 0, 0};
        p.n0 = 16; p.n1 = 64; p.n2 = 64; p.n3 = 0;
        gstage<<<144, 256, 0, stream>>>(p);
    }
    // K3: [S2;S3] = [S0;S1]@P2  ||  P8 = P4@P4  ||  T3 = T2 + T2@P4
    {
        Pack p; p.j[3] = dummy;
        p.j[0] = {stack, nullptr, P2, nullptr, stack + 256 * H_, nullptr, 256, 512, 512, 8, 4, 0, 0};
        p.j[1] = {P4, nullptr, P4, nullptr, P8, nullptr, 512, 512, 512, 8, 8, 0, 0};
        p.j[2] = {T2, nullptr, P4, T2, T3, nullptr, 512, 512, 512, 8, 8, 0, 0};
        p.n0 = 32; p.n1 = 64; p.n2 = 64; p.n3 = 0;
        gstage<<<160, 256, 0, stream>>>(p);
    }
    // K4: [S4..S7] = [S0..S3]@P4  ||  C1 = P8@P8 (A^16)  ||  T4 = T3 + T3@P8
    {
        Pack p; p.j[3] = dummy;
        p.j[0] = {stack, nullptr, P4, nullptr, stack + 512 * H_, nullptr, 512, 512, 512, 8, 8, 0, 0};
        p.j[1] = {P8, nullptr, P8, nullptr, C1, nullptr, 512, 512, 512, 8, 8, 0, 0};
        p.j[2] = {T3, nullptr, P8, T3, T4, nullptr, 512, 512, 512, 8, 8, 0, 0};
        p.n0 = 64; p.n1 = 64; p.n2 = 64; p.n3 = 0;
        gstage<<<192, 256, 0, stream>>>(p);
    }
    // K5: [S8..S15] = [S0..S7]@P8  ||  C2p = C1@C1 (A^32)  ||  T5 = T4 + T4@C1
    {
        Pack p; p.j[3] = dummy;
        p.j[0] = {stack, nullptr, P8, nullptr, stack + 1024 * H_, nullptr, 1024, 512, 512, 8, 16, 0, 0};
        p.j[1] = {C1, nullptr, C1, nullptr, C2p, nullptr, 512, 512, 512, 8, 8, 0, 0};
        p.j[2] = {T4, nullptr, C1, T4, T5, nullptr, 512, 512, 512, 8, 8, 0, 0};
        p.n0 = 128; p.n1 = 64; p.n2 = 64; p.n3 = 0;
        gstage<<<256, 256, 0, stream>>>(p);
    }
    // K6: G = xcat@stack (K=2048, split4 slabs)  ||  C3=C1@C2p  ||  C4=C2p@C2p
    //     ||  T6 = T5 + T5@C2p
    {
        Pack p;
        p.j[0] = {x, nullptr, stack, nullptr, G, nullptr, 128, 0, 512, 8, 2, 2, 0};
        p.j[1] = {C1, nullptr, C2p, nullptr, C3, nullptr, 512, 512, 512, 8, 8, 0, 0};
        p.j[2] = {C2p, nullptr, C2p, nullptr, C4, nullptr, 512, 512, 512, 8, 8, 0, 0};
        p.j[3] = {T5, nullptr, C2p, T5, T6, nullptr, 512, 512, 512, 8, 8, 0, 0};
        p.n0 = 64; p.n1 = 64; p.n2 = 64; p.n3 = 64;
        gstage<<<256, 256, 0, stream>>>(p);
    }
    TP tp;
    tp.G = G; tp.Hp = Hp; tp.C1 = C1; tp.C2p = C2p; tp.C3 = C3; tp.C4 = C4;
    tp.T7 = T7; tp.bc = bc; tp.x = x; tp.Wr = Wr; tp.zn = zn; tp.W1 = W1;
    tp.h1p = h1p; tp.b1 = b1; tp.W2 = W2;

    // K7: Hp (K=1536, 3 slabs, 2 row-groups)  ||  T7 = T6 + T6@C4
    {
        TP t = tp; t.outp = Hp; t.nbx = 8; t.nrg = 2; t.kLen = 512;
        Job gj = {T6, nullptr, C4, T6, T7, nullptr, 512, 512, 512, 8, 8, 0, 0};
        tstage<0, true><<<48 + 64, 256, 0, stream>>>(t, gj, 48);
    }
    // K8: zp = [H1|bc|x_last]@[C4;T7;Wr] (K=1152, 9 slabs)
    {
        TP t = tp; t.outp = zp; t.nbx = 8; t.nrg = 1; t.kLen = 128;
        tstage<1, false><<<72, 256, 0, stream>>>(t, dummy, 1 << 30);
    }
    // K9: zln
    zln<<<16, 256, 0, stream>>>(zp, Hp, G, br, lng, lnb, zn);
    // K10: h1p = zn@W1 (K=512, 4 slabs x 16 col-tiles)
    {
        TP t = tp; t.outp = h1p; t.nbx = 16; t.nrg = 1; t.kLen = 128;
        tstage<2, false><<<64, 256, 0, stream>>>(t, dummy, 1 << 30);
    }
    // K11: op = relu(b1+sum h1p)@W2 (K=1024, 8 slabs x 8 col-tiles)
    {
        TP t = tp; t.outp = op; t.nbx = 8; t.nrg = 1; t.kLen = 128;
        tstage<3, false><<<64, 256, 0, stream>>>(t, dummy, 1 << 30);
    }
    // K12: out = b2 + sum op
    ored<<<32, 256, 0, stream>>>(op, b2, out);
}

// Round 8
// 342.759 us; speedup vs baseline: 2.3926x; 1.2492x over previous
//
#include <hip/hip_runtime.h>

#define B_  16
#define T_  2048
#define L_  128
#define H_  512
#define F_  1024
#define EPS 1e-5f

#define GP   68                 // 64+4 LDS pad
#define GSM  (64 * GP * 2)      // 34816 B -> 4 blocks/CU LDS cap

#define SS_P (512 * 512)        // power slab stride

// ---------------------------------------------------------------------------
// Job for the 64x64-tile GEMM (BK=64, TM=TN=4, 256 thr), split-K slabs.
// amode: 0 dense row-major (A slab-sum nsA/ssA);
//        1 Wc: rows<128 from A(lda), row128 from Aaux(be), out row128->C2;
//        2 tree: A-row -> pred[((r>>4)<<5)+16+(r&15)] (slab-sum), kc==0 block
//          epilogue adds pred[((r>>4)<<5)+(r&15)] (slab-sum over Add=pred);
//        3 x-gather: row r=(lag*16+b) -> x[b][T-1-lag][:], epilogue +Aaux[c];
//        9 slab-reduce: C = sum_{s<nsA} A[s*ssA + i] (elementwise, 32 blocks)
// Output: C + kc*M*512 (slab per kc). kLen = K per chunk (multiple of 64).
// ---------------------------------------------------------------------------
struct Job {
    const float* A; const float* Aaux; const float* B; const float* Add;
    float* C; float* C2;
    int M, lda, kLen, nbx, nrt, amode, nsA, ssA, nsB, ssB;
};

__device__ __forceinline__ float4 jloadA(const Job& jb, int gr, int gk) {
    if (jb.amode == 1) {
        if (gr < 128)  return *(const float4*)(jb.A + (long)gr * jb.lda + gk);
        if (gr == 128) return *(const float4*)(jb.Aaux + gk);
        return make_float4(0.f, 0.f, 0.f, 0.f);
    }
    if (jb.amode == 3) {
        int b = gr & 15, lag = gr >> 4;
        return *(const float4*)(jb.A + ((long)b * T_ + (T_ - 1 - lag)) * L_ + gk);
    }
    int row = gr;
    if (jb.amode == 2) row = ((gr >> 4) << 5) + 16 + (gr & 15);
    else if (gr >= jb.M) return make_float4(0.f, 0.f, 0.f, 0.f);
    const float* p = jb.A + (long)row * 512 + gk;
    float4 s = *(const float4*)p;
    for (int q = 1; q < jb.nsA; ++q) {
        float4 t = *(const float4*)(p + (long)q * jb.ssA);
        s.x += t.x; s.y += t.y; s.z += t.z; s.w += t.w;
    }
    return s;
}

__device__ __forceinline__ float4 jloadB(const Job& jb, int gk, int c) {
    const float* p = jb.B + (long)gk * 512 + c;
    float4 s = *(const float4*)p;
    for (int q = 1; q < jb.nsB; ++q) {
        float4 t = *(const float4*)(p + (long)q * jb.ssB);
        s.x += t.x; s.y += t.y; s.z += t.z; s.w += t.w;
    }
    return s;
}

__device__ __forceinline__ void g64run(float* sm, const Job& jb, int rel) {
    float* As = sm;                 // [64][68] As[k][m]
    float* Bs = sm + 64 * GP;       // [64][68] Bs[k][n]
    const int tid = threadIdx.x, tx = tid & 15, ty = tid >> 4;
    const int bx = rel % jb.nbx;
    const int r  = rel / jb.nbx;
    const int by = r % jb.nrt;
    const int kc = r / jb.nrt;
    const int row0 = by * 64, col0 = bx * 64, kOff = kc * jb.kLen;

    float4 pa[4], pb[4];
#pragma unroll
    for (int t = 0; t < 4; ++t) {
        int f = tid + t * 256;
        pa[t] = jloadA(jb, row0 + (f >> 4), kOff + (f & 15) * 4);
        pb[t] = jloadB(jb, kOff + (f >> 4), col0 + (f & 15) * 4);
    }
    float acc[4][4] = {};
    for (int k0 = 0; k0 < jb.kLen; k0 += 64) {
        __syncthreads();
#pragma unroll
        for (int t = 0; t < 4; ++t) {
            int f = tid + t * 256;
            int ar = f >> 4, ak = (f & 15) * 4;
            As[(ak + 0) * GP + ar] = pa[t].x;
            As[(ak + 1) * GP + ar] = pa[t].y;
            As[(ak + 2) * GP + ar] = pa[t].z;
            As[(ak + 3) * GP + ar] = pa[t].w;
            *(float4*)&Bs[(f >> 4) * GP + (f & 15) * 4] = pb[t];
        }
        __syncthreads();
        int kn = k0 + 64;
        if (kn < jb.kLen) {
#pragma unroll
            for (int t = 0; t < 4; ++t) {
                int f = tid + t * 256;
                pa[t] = jloadA(jb, row0 + (f >> 4), kOff + kn + (f & 15) * 4);
                pb[t] = jloadB(jb, kOff + kn + (f >> 4), col0 + (f & 15) * 4);
            }
        }
#pragma unroll
        for (int kk = 0; kk < 64; ++kk) {
            float4 ra = *(float4*)&As[kk * GP + ty * 4];
            float4 rb = *(float4*)&Bs[kk * GP + tx * 4];
            acc[0][0] = fmaf(ra.x, rb.x, acc[0][0]);
            acc[0][1] = fmaf(ra.x, rb.y, acc[0][1]);
            acc[0][2] = fmaf(ra.x, rb.z, acc[0][2]);
            acc[0][3] = fmaf(ra.x, rb.w, acc[0][3]);
            acc[1][0] = fmaf(ra.y, rb.x, acc[1][0]);
            acc[1][1] = fmaf(ra.y, rb.y, acc[1][1]);
            acc[1][2] = fmaf(ra.y, rb.z, acc[1][2]);
            acc[1][3] = fmaf(ra.y, rb.w, acc[1][3]);
            acc[2][0] = fmaf(ra.z, rb.x, acc[2][0]);
            acc[2][1] = fmaf(ra.z, rb.y, acc[2][1]);
            acc[2][2] = fmaf(ra.z, rb.z, acc[2][2]);
            acc[2][3] = fmaf(ra.z, rb.w, acc[2][3]);
            acc[3][0] = fmaf(ra.w, rb.x, acc[3][0]);
            acc[3][1] = fmaf(ra.w, rb.y, acc[3][1]);
            acc[3][2] = fmaf(ra.w, rb.z, acc[3][2]);
            acc[3][3] = fmaf(ra.w, rb.w, acc[3][3]);
        }
    }
    long coff = (long)kc * jb.M * 512;
#pragma unroll
    for (int i = 0; i < 4; ++i) {
        int rr = row0 + ty * 4 + i;
        if (rr >= jb.M) continue;
        int c = col0 + tx * 4;
        float4 v = make_float4(acc[i][0], acc[i][1], acc[i][2], acc[i][3]);
        if (jb.amode == 2 && kc == 0) {
            long prow = (long)(((rr >> 4) << 5) + (rr & 15)) * 512;
            const float* ap = jb.Add + prow + c;
            for (int q = 0; q < jb.nsA; ++q) {
                float4 ad = *(const float4*)(ap + (long)q * jb.ssA);
                v.x += ad.x; v.y += ad.y; v.z += ad.z; v.w += ad.w;
            }
        }
        if (jb.amode == 3) {
            v.x += jb.Aaux[c]; v.y += jb.Aaux[c + 1];
            v.z += jb.Aaux[c + 2]; v.w += jb.Aaux[c + 3];
        }
        if (jb.amode == 1 && rr == 128)
            *(float4*)(jb.C2 + c) = v;
        else
            *(float4*)(jb.C + coff + (long)rr * 512 + c) = v;
    }
}

struct Pack { Job j[3]; int n0, n1; };

__global__ __launch_bounds__(256) void gstage(Pack p) {
    __shared__ float sm[GSM];
    int b = blockIdx.x, rel;
    const Job* jb;
    if (b < p.n0) { jb = &p.j[0]; rel = b; }
    else if (b < p.n0 + p.n1) { jb = &p.j[1]; rel = b - p.n0; }
    else { jb = &p.j[2]; rel = b - p.n0 - p.n1; }
    if (jb->amode == 9) {              // slab reduce: 32 blocks, float4 stride
        const float4* src = (const float4*)jb->A;
        float4* dst = (float4*)jb->C;
        int ss4 = jb->ssA >> 2;
        for (int i = rel * 256 + threadIdx.x; i < SS_P / 4; i += 32 * 256) {
            float4 s = src[i];
            for (int q = 1; q < jb->nsA; ++q) {
                float4 t = src[i + q * ss4];
                s.x += t.x; s.y += t.y; s.z += t.z; s.w += t.w;
            }
            dst[i] = s;
        }
        return;
    }
    g64run(sm, *jb, rel);
}

// ---------------------------------------------------------------------------
// Tail split-K GEMM: BM=16, BN=64, BK=64, 4 out/thread, slab outputs.
// MODE 0 (z): A=[sum8 Y5s nodes1..3 | x_last] K=1664, B=[P32;P64;sum4 P96s;Wr]
// MODE 1: A=zn, B=W1 (ldb=1024)
// MODE 2: A=relu(b1+sum4 h1p), B=W2
// ---------------------------------------------------------------------------
struct TP {
    const float* Y5s; const float* P32; const float* P64; const float* P96s;
    const float* x; const float* Wr; const float* zn; const float* W1;
    const float* h1p; const float* b1; const float* W2;
    float* outp; int nbx, kLen;
};

template <int MODE>
__device__ __forceinline__ float4 ta4(const TP& tp, int b, int gk) {
    if (MODE == 0) {
        if (gk < 1536) {
            int seg = gk >> 9, inner = gk & 511;
            const float* p = tp.Y5s + (long)((seg + 1) * 16 + b) * 512 + inner;
            float4 s = *(const float4*)p;
#pragma unroll
            for (int q = 1; q < 8; ++q) {
                float4 t = *(const float4*)(p + (long)q * 64 * 512);
                s.x += t.x; s.y += t.y; s.z += t.z; s.w += t.w;
            }
            return s;
        }
        return *(const float4*)(tp.x + ((long)b * T_ + T_ - 1) * L_ + gk - 1536);
    } else if (MODE == 1) {
        return *(const float4*)(tp.zn + (long)b * H_ + gk);
    } else {
        float4 s = *(const float4*)(tp.b1 + gk);
#pragma unroll
        for (int q = 0; q < 4; ++q) {
            float4 h = *(const float4*)(tp.h1p + (long)q * 16 * F_ + (long)b * F_ + gk);
            s.x += h.x; s.y += h.y; s.z += h.z; s.w += h.w;
        }
        return make_float4(fmaxf(s.x, 0.f), fmaxf(s.y, 0.f),
                           fmaxf(s.z, 0.f), fmaxf(s.w, 0.f));
    }
}

template <int MODE>
__device__ __forceinline__ float4 tb4(const TP& tp, int kr, int c) {
    if (MODE == 0) {
        if (kr < 512)  return *(const float4*)(tp.P32 + (long)kr * 512 + c);
        if (kr < 1024) return *(const float4*)(tp.P64 + (long)(kr - 512) * 512 + c);
        if (kr < 1536) {
            const float* p = tp.P96s + (long)(kr - 1024) * 512 + c;
            float4 s = *(const float4*)p;
#pragma unroll
            for (int q = 1; q < 4; ++q) {
                float4 t = *(const float4*)(p + (long)q * SS_P);
                s.x += t.x; s.y += t.y; s.z += t.z; s.w += t.w;
            }
            return s;
        }
        return *(const float4*)(tp.Wr + (long)(kr - 1536) * 512 + c);
    } else if (MODE == 1) {
        return *(const float4*)(tp.W1 + (long)kr * F_ + c);
    } else {
        return *(const float4*)(tp.W2 + (long)kr * H_ + c);
    }
}

template <int MODE>
__global__ __launch_bounds__(256) void tstage(TP tp) {
    constexpr int LDC = (MODE == 1) ? F_ : H_;
    __shared__ float sm[64 * 20 + 64 * 68];
    float* As = sm;
    float* Bs = sm + 64 * 20;
    const int tid = threadIdx.x, tx = tid & 15, ty = tid >> 4;
    const int kc = blockIdx.x / tp.nbx;
    const int col0 = (blockIdx.x % tp.nbx) * 64;
    const int kOff = kc * tp.kLen;

    float4 pa, pb[4];
    pa = ta4<MODE>(tp, ty, kOff + tx * 4);
#pragma unroll
    for (int t = 0; t < 4; ++t) {
        int f = tid + t * 256;
        pb[t] = tb4<MODE>(tp, kOff + (f >> 4), col0 + (f & 15) * 4);
    }
    float acc[4] = {};
    for (int k0 = 0; k0 < tp.kLen; k0 += 64) {
        __syncthreads();
        {
            int kk = tx * 4;
            As[(kk + 0) * 20 + ty] = pa.x;
            As[(kk + 1) * 20 + ty] = pa.y;
            As[(kk + 2) * 20 + ty] = pa.z;
            As[(kk + 3) * 20 + ty] = pa.w;
        }
#pragma unroll
        for (int t = 0; t < 4; ++t) {
            int f = tid + t * 256;
            *(float4*)&Bs[(f >> 4) * 68 + (f & 15) * 4] = pb[t];
        }
        __syncthreads();
        int kn = k0 + 64;
        if (kn < tp.kLen) {
            pa = ta4<MODE>(tp, ty, kOff + kn + tx * 4);
#pragma unroll
            for (int t = 0; t < 4; ++t) {
                int f = tid + t * 256;
                pb[t] = tb4<MODE>(tp, kOff + kn + (f >> 4), col0 + (f & 15) * 4);
            }
        }
#pragma unroll
        for (int kk = 0; kk < 64; ++kk) {
            float ra = As[kk * 20 + ty];
            float4 rb = *(float4*)&Bs[kk * 68 + tx * 4];
            acc[0] = fmaf(ra, rb.x, acc[0]);
            acc[1] = fmaf(ra, rb.y, acc[1]);
            acc[2] = fmaf(ra, rb.z, acc[2]);
            acc[3] = fmaf(ra, rb.w, acc[3]);
        }
    }
    float* dst = tp.outp + (long)kc * 16 * LDC + (long)ty * LDC + col0 + tx * 4;
    *(float4*)dst = make_float4(acc[0], acc[1], acc[2], acc[3]);
}

// z = br + sum13 zp + sum8 Y5s(node0); LayerNorm -> zn.  grid=16
__global__ __launch_bounds__(256) void zln(
    const float* __restrict__ zp, const float* __restrict__ Y5s,
    const float* __restrict__ br, const float* __restrict__ lng,
    const float* __restrict__ lnb, float* __restrict__ zn)
{
    __shared__ float red1[4], red2[4];
    const int b = blockIdx.x, tid = threadIdx.x;
    float z[2];
#pragma unroll
    for (int jj = 0; jj < 2; ++jj) {
        int c = tid + jj * 256;
        float s = br[c];
#pragma unroll
        for (int q = 0; q < 13; ++q) s += zp[(long)q * 16 * H_ + (long)b * H_ + c];
#pragma unroll
        for (int q = 0; q < 8; ++q) s += Y5s[(long)q * 64 * 512 + (long)b * 512 + c];
        z[jj] = s;
    }
    float s1 = z[0] + z[1];
    float s2 = z[0] * z[0] + z[1] * z[1];
#pragma unroll
    for (int off = 32; off > 0; off >>= 1) {
        s1 += __shfl_down(s1, off, 64);
        s2 += __shfl_down(s2, off, 64);
    }
    int wid = tid >> 6, lane = tid & 63;
    if (lane == 0) { red1[wid] = s1; red2[wid] = s2; }
    __syncthreads();
    float S1 = red1[0] + red1[1] + red1[2] + red1[3];
    float S2 = red2[0] + red2[1] + red2[2] + red2[3];
    float mu  = S1 * (1.0f / H_);
    float var = S2 * (1.0f / H_) - mu * mu;
    float rs  = rsqrtf(var + EPS);
#pragma unroll
    for (int jj = 0; jj < 2; ++jj) {
        int c = tid + jj * 256;
        zn[(long)b * H_ + c] = (z[jj] - mu) * rs * lng[c] + lnb[c];
    }
}

// out = b2 + sum8 op.  grid=32
__global__ __launch_bounds__(256) void ored(
    const float* __restrict__ op, const float* __restrict__ b2,
    float* __restrict__ out)
{
    int b = blockIdx.x >> 1;
    int c = (blockIdx.x & 1) * 256 + threadIdx.x;
    float s = b2[c];
#pragma unroll
    for (int q = 0; q < 8; ++q) s += op[(long)q * 16 * H_ + (long)b * H_ + c];
    out[(long)b * H_ + c] = s;
}

// ---------------------------------------------------------------------------
extern "C" void kernel_launch(void* const* d_in, const int* in_sizes, int n_in,
                              void* d_out, int out_size, void* d_ws, size_t ws_size,
                              hipStream_t stream) {
    const float* x    = (const float*)d_in[0];
    const float* We   = (const float*)d_in[1];
    const float* be   = (const float*)d_in[2];
    const float* Wb   = (const float*)d_in[3];
    const float* Amat = (const float*)d_in[4];
    const float* Wr   = (const float*)d_in[5];
    const float* br   = (const float*)d_in[6];
    const float* lng  = (const float*)d_in[7];
    const float* lnb  = (const float*)d_in[8];
    const float* W1   = (const float*)d_in[9];
    const float* b1   = (const float*)d_in[10];
    const float* W2   = (const float*)d_in[11];
    const float* b2   = (const float*)d_in[12];
    float* out = (float*)d_out;

    float* ws   = (float*)d_ws;
    float* Wc   = ws;                        // 128x512
    float* bc   = Wc + 128 * 512;            // 512
    float* U0   = bc + 512;                  // 2048x512 (dense)
    float* Y1s  = U0 + 2048 * 512;           // 2 x 1024x512
    float* Y2s  = Y1s + 2 * 1024 * 512;      // 2 x 512x512
    float* Y3s  = Y2s + 2 * 512 * 512;       // 4 x 256x512
    float* Y4s  = Y3s + 4 * 256 * 512;       // 4 x 128x512
    float* Y5s  = Y4s + 4 * 128 * 512;       // 8 x 64x512
    float* P2s  = Y5s + 8 * 64 * 512;        // 4 x 512^2 slabs each:
    float* P4s  = P2s + 4 * SS_P;
    float* P8s  = P4s + 4 * SS_P;
    float* P16s = P8s + 4 * SS_P;
    float* P32s = P16s + 4 * SS_P;
    float* P64s = P32s + 4 * SS_P;
    float* P96s = P64s + 4 * SS_P;
    float* P2d  = P96s + 4 * SS_P;           // dense reductions:
    float* P4d  = P2d + SS_P;
    float* P8d  = P4d + SS_P;
    float* P16d = P8d + SS_P;
    float* P32d = P16d + SS_P;
    float* P64d = P32d + SS_P;
    float* zp   = P64d + SS_P;               // 13 x 16 x 512
    float* zn   = zp + 13 * B_ * H_;         // 16 x 512
    float* h1p  = zn + B_ * H_;              // 4 x 16 x 1024
    float* op   = h1p + 4 * B_ * F_;         // 8 x 16 x 512

    Job dummy = {}; dummy.amode = 9; dummy.nsA = 1; dummy.ssA = 4;
    dummy.A = Wc; dummy.C = Wc;              // never dispatched

    // S0: Wc=[We;be]@Wb (24)  ||  P2s = A@A split4 (256)
    {
        Pack p; p.j[2] = dummy;
        p.j[0] = {We, be, Wb, nullptr, Wc, bc, 129, 256, 256, 8, 3, 1, 1, 0, 1, 0};
        p.j[1] = {Amat, nullptr, Amat, nullptr, P2s, nullptr, 512, 512, 128, 8, 8, 0, 1, 0, 1, 0};
        p.n0 = 24; p.n1 = 256;
        gstage<<<280, 256, 0, stream>>>(p);
    }
    // S1: U0 = x-gather@Wc + bc (256)  ||  P4s = P2s^2 (256)  ||  P2red (32)
    {
        Pack p;
        p.j[0] = {x, bc, Wc, nullptr, U0, nullptr, 2048, 0, 128, 8, 32, 3, 1, 0, 1, 0};
        p.j[1] = {P2s, nullptr, P2s, nullptr, P4s, nullptr, 512, 512, 128, 8, 8, 0, 4, SS_P, 4, SS_P};
        p.j[2] = {P2s, nullptr, nullptr, nullptr, P2d, nullptr, 512, 512, 64, 1, 1, 9, 4, SS_P, 1, 0};
        p.n0 = 256; p.n1 = 256;
        gstage<<<544, 256, 0, stream>>>(p);
    }
    // S2: Y1s = tree(U0)@A split2 (256)  ||  P8s (256)  ||  P4red (32)
    {
        Pack p;
        p.j[0] = {U0, nullptr, Amat, U0, Y1s, nullptr, 1024, 512, 256, 8, 16, 2, 1, 0, 1, 0};
        p.j[1] = {P4s, nullptr, P4s, nullptr, P8s, nullptr, 512, 512, 128, 8, 8, 0, 4, SS_P, 4, SS_P};
        p.j[2] = {P4s, nullptr, nullptr, nullptr, P4d, nullptr, 512, 512, 64, 1, 1, 9, 4, SS_P, 1, 0};
        p.n0 = 256; p.n1 = 256;
        gstage<<<544, 256, 0, stream>>>(p);
    }
    // S3: Y2s = tree(sum2 Y1s)@P2d split2 (128)  ||  P16s (256)  ||  P8red (32)
    {
        Pack p;
        p.j[0] = {Y1s, nullptr, P2d, Y1s, Y2s, nullptr, 512, 512, 256, 8, 8, 2, 2, 1024 * 512, 1, 0};
        p.j[1] = {P8s, nullptr, P8s, nullptr, P16s, nullptr, 512, 512, 128, 8, 8, 0, 4, SS_P, 4, SS_P};
        p.j[2] = {P8s, nullptr, nullptr, nullptr, P8d, nullptr, 512, 512, 64, 1, 1, 9, 4, SS_P, 1, 0};
        p.n0 = 128; p.n1 = 256;
        gstage<<<416, 256, 0, stream>>>(p);
    }
    // S4: Y3s = tree(sum2 Y2s)@P4d split4 (128)  ||  P32s (256)  ||  P16red (32)
    {
        Pack p;
        p.j[0] = {Y2s, nullptr, P4d, Y2s, Y3s, nullptr, 256, 512, 128, 8, 4, 2, 2, 512 * 512, 1, 0};
        p.j[1] = {P16s, nullptr, P16s, nullptr, P32s, nullptr, 512, 512, 128, 8, 8, 0, 4, SS_P, 4, SS_P};
        p.j[2] = {P16s, nullptr, nullptr, nullptr, P16d, nullptr, 512, 512, 64, 1, 1, 9, 4, SS_P, 1, 0};
        p.n0 = 128; p.n1 = 256;
        gstage<<<416, 256, 0, stream>>>(p);
    }
    // S5: Y4s = tree(sum4 Y3s)@P8d split4 (64)  ||  P64s (256)  ||  P32red (32)
    {
        Pack p;
        p.j[0] = {Y3s, nullptr, P8d, Y3s, Y4s, nullptr, 128, 512, 128, 8, 2, 2, 4, 256 * 512, 1, 0};
        p.j[1] = {P32s, nullptr, P32s, nullptr, P64s, nullptr, 512, 512, 128, 8, 8, 0, 4, SS_P, 4, SS_P};
        p.j[2] = {P32s, nullptr, nullptr, nullptr, P32d, nullptr, 512, 512, 64, 1, 1, 9, 4, SS_P, 1, 0};
        p.n0 = 64; p.n1 = 256;
        gstage<<<352, 256, 0, stream>>>(p);
    }
    // S6: Y5s = tree(sum4 Y4s)@P16d split8 (64)  ||  P96s = P32d@P64s (256)
    //     ||  P64red (32)
    {
        Pack p;
        p.j[0] = {Y4s, nullptr, P16d, Y4s, Y5s, nullptr, 64, 512, 64, 8, 1, 2, 4, 128 * 512, 1, 0};
        p.j[1] = {P32d, nullptr, P64s, nullptr, P96s, nullptr, 512, 512, 128, 8, 8, 0, 1, 0, 4, SS_P};
        p.j[2] = {P64s, nullptr, nullptr, nullptr, P64d, nullptr, 512, 512, 64, 1, 1, 9, 4, SS_P, 1, 0};
        p.n0 = 64; p.n1 = 256;
        gstage<<<352, 256, 0, stream>>>(p);
    }
    TP tp;
    tp.Y5s = Y5s; tp.P32 = P32d; tp.P64 = P64d; tp.P96s = P96s;
    tp.x = x; tp.Wr = Wr; tp.zn = zn; tp.W1 = W1; tp.h1p = h1p;
    tp.b1 = b1; tp.W2 = W2;

    // S7: zp (K=1664, 13 kc x 8 col-tiles)
    { TP t = tp; t.outp = zp; t.nbx = 8; t.kLen = 128;
      tstage<0><<<104, 256, 0, stream>>>(t); }
    // S8: zln
    zln<<<16, 256, 0, stream>>>(zp, Y5s, br, lng, lnb, zn);
    // S9: h1p = zn@W1 (K=512, 4 kc x 16)
    { TP t = tp; t.outp = h1p; t.nbx = 16; t.kLen = 128;
      tstage<1><<<64, 256, 0, stream>>>(t); }
    // S10: op = relu(b1+sum h1p)@W2 (K=1024, 8 kc x 8)
    { TP t = tp; t.outp = op; t.nbx = 8; t.kLen = 128;
      tstage<2><<<64, 256, 0, stream>>>(t); }
    // S11: out = b2 + sum op
    ored<<<32, 256, 0, stream>>>(op, b2, out);
}